// Round 7
// baseline (17.340 us; speedup 1.0000x reference)
//
#include <hip/hip_runtime.h>
#include <hip/hip_bf16.h>

// Fully fused, band=4. Grid 448 blocks (64 opair x 7 band), 448 threads
// (7 waves). LDS 56,320B -> 2 blocks/CU -> 14 waves/CU.
//
// Phase A: exactly one task per thread (tid<384): task = (c, pr); sliding
//   window float4 stage-1 into sA[c][pr][36], channel stride 220.
// Phase B: tid = (strip<<3)|l8; strip = (oo, dh, st) = 2*4*7 = 56, l8 = 8-way
//   l-split. Thread: 1x4 output strip, l = l8+8*li (li 0..3), both k-parities.
//   288 FMA/thread. 3-step shfl_xor reduce; lane l8==0 stores float4.
// Weights prefetched to registers (float4 loads) BEFORE phase A.
__global__ __launch_bounds__(448, 2) void fused_kernel(
    const float* __restrict__ x,    // [64][28][28]
    const float* __restrict__ w1,   // [128][32][3][3][2]
    const float* __restrict__ w2,   // [64][3][2]
    float* __restrict__ y)          // [128][28][28]
{
    __shared__ __align__(16) float sA[64 * 220];   // 56,320 B

    const int b     = blockIdx.x;     // 0..447
    const int opair = b / 7;
    const int band  = b % 7;
    const int tid   = threadIdx.x;    // 0..447

    // ---------------- Phase B thread mapping ----------------
    const int l8    = tid & 7;        // lane bits 0-2: l-split
    const int strip = tid >> 3;       // 0..55
    const int oo    = strip / 28;
    const int rr    = strip % 28;
    const int dh    = rr / 7;         // output row within band
    const int st    = rr % 7;         // 4-col strip
    const int o     = opair * 2 + oo;

    // ---------------- Weight prefetch (before phase A) ----------------
    // wl[li][dy*6 + s*2 + k], statically indexed after unroll -> registers.
    float wl[4][18];
    {
        const float* wb = w1 + o * 576 + l8 * 18;   // w1[o][l][dy][s][k]
        #pragma unroll
        for (int li = 0; li < 4; ++li) {
            const float* p = wb + li * 144;         // +8l*18
            #pragma unroll
            for (int t = 0; t < 4; ++t)
                *(float4*)&wl[li][t * 4] = *(const float4*)(p + t * 4);
            *(float2*)&wl[li][16] = *(const float2*)(p + 16);
        }
    }

    // ---------------- Phase A: stage1+2 into LDS (1 task/thread) ----------
    if (tid < 384) {
        const int c  = tid / 6;
        const int pr = tid % 6;
        const int m  = band * 4 + pr - 1;   // input row for padded row
        float* dst = &sA[c * 220 + pr * 36];
        if (m < 0 || m > 27) {
            #pragma unroll
            for (int t = 0; t < 7; ++t)
                ((float4*)dst)[t] = make_float4(0.f, 0.f, 0.f, 0.f);
            ((float2*)dst)[14] = make_float2(0.f, 0.f);
        } else {
            const int j0 = c & ~1;
            const int k  = c & 1;
            const float* xr0 = x + (j0 * 28 + m) * 28;
            const float* xr1 = xr0 + 28 * 28;
            const float* w2p = w2 + j0 * 6 + k;
            const float wa0 = w2p[0], wa1 = w2p[2],  wa2 = w2p[4];
            const float wb0 = w2p[6], wb1 = w2p[8],  wb2 = w2p[10];

            float4 pv0 = make_float4(0.f, 0.f, 0.f, 0.f);
            float4 pv1 = make_float4(0.f, 0.f, 0.f, 0.f);
            #pragma unroll
            for (int t = 0; t < 7; ++t) {
                float4 v0 = ((const float4*)xr0)[t];
                float4 v1 = ((const float4*)xr1)[t];
                float4 ov;
                ov.x = wa0 * pv0.z + wa1 * pv0.w + wa2 * v0.x
                     + wb0 * pv1.z + wb1 * pv1.w + wb2 * v1.x;
                ov.y = wa0 * pv0.w + wa1 * v0.x + wa2 * v0.y
                     + wb0 * pv1.w + wb1 * v1.x + wb2 * v1.y;
                ov.z = wa0 * v0.x + wa1 * v0.y + wa2 * v0.z
                     + wb0 * v1.x + wb1 * v1.y + wb2 * v1.z;
                ov.w = wa0 * v0.y + wa1 * v0.z + wa2 * v0.w
                     + wb0 * v1.y + wb1 * v1.z + wb2 * v1.w;
                if (t == 0) ov.x = 0.f;     // px 0 is left zero-pad
                ((float4*)dst)[t] = ov;
                pv0 = v0; pv1 = v1;
            }
            // px 28 (taps xr[26], xr[27]) and px 29 (right pad)
            float t28 = wa0 * pv0.z + wa1 * pv0.w
                      + wb0 * pv1.z + wb1 * pv1.w;
            ((float2*)dst)[14] = make_float2(t28, 0.f);
        }
    }
    __syncthreads();

    // ---------------- Phase B: 3x3x64 conv, 1x4 strip ----------------
    float acc0 = 0.f, acc1 = 0.f, acc2 = 0.f, acc3 = 0.f;

    #pragma unroll
    for (int li = 0; li < 4; ++li) {
        #pragma unroll
        for (int ch = 0; ch < 2; ++ch) {
            const int c = (l8 + li * 8) * 2 + ch;
            const float* sa = &sA[c * 220 + dh * 36 + st * 4];
            #pragma unroll
            for (int dy = 0; dy < 3; ++dy) {
                const float wa  = wl[li][dy * 6 + 0 + ch];
                const float wbv = wl[li][dy * 6 + 2 + ch];
                const float wc  = wl[li][dy * 6 + 4 + ch];
                const float* rA = sa + dy * 36;
                float4 t0 = *(const float4*)rA;
                float2 t1 = *(const float2*)(rA + 4);
                acc0 += wa * t0.x + wbv * t0.y + wc * t0.z;
                acc1 += wa * t0.y + wbv * t0.z + wc * t0.w;
                acc2 += wa * t0.z + wbv * t0.w + wc * t1.x;
                acc3 += wa * t0.w + wbv * t1.x + wc * t1.y;
            }
        }
    }

    // butterfly reduce over l8 (lane bits 0-2)
    #pragma unroll
    for (int m = 1; m <= 4; m <<= 1) {
        acc0 += __shfl_xor(acc0, m);
        acc1 += __shfl_xor(acc1, m);
        acc2 += __shfl_xor(acc2, m);
        acc3 += __shfl_xor(acc3, m);
    }

    if (l8 == 0) {
        const int R = band * 4 + dh;
        float* yp = y + (o * 28 + R) * 28 + st * 4;
        *(float4*)yp = make_float4(acc0, acc1, acc2, acc3);
    }
}

extern "C" void kernel_launch(void* const* d_in, const int* in_sizes, int n_in,
                              void* d_out, int out_size, void* d_ws, size_t ws_size,
                              hipStream_t stream) {
    const float* x  = (const float*)d_in[0];   // (1,64,28,28) fp32
    const float* w1 = (const float*)d_in[1];   // (128,32,3,3,2) fp32
    const float* w2 = (const float*)d_in[2];   // (64,3,2) fp32
    float* yout = (float*)d_out;               // (1,128,28,28) fp32

    fused_kernel<<<dim3(448), dim3(448), 0, stream>>>(x, w1, w2, yout);
}

// Round 8
// 13.875 us; speedup vs baseline: 1.2497x; 1.2497x over previous
//
#include <hip/hip_runtime.h>
#include <hip/hip_bf16.h>

// Fully fused, band=4. Grid 448 blocks (64 opair x 7 band) x 256 threads.
// LDS 56,320B -> 2 blocks/CU -> 8 waves/CU.
//
// Phase A (l-paired, single round): 192 tasks = (l 0..31, pr 0..5). Each task
//   loads x rows 2l and 2l+1 ONCE (14 float4) and produces BOTH stage-1
//   channels c=2l (k=0) and c=2l+1 (k=1) via the float2 k-pair weights.
//   Halves global x traffic and the worst-case phase-A chain vs the ragged
//   1.5-round version.
// Phase B (R6-proven): thread = (oo, rp, st, l8). 2x4 output tile, 8-way
//   l-split on lane bits 0-2, weights prefetched to registers before phase A,
//   3-step shfl_xor reduce, lane l8==0 stores two float4.
__global__ __launch_bounds__(256, 2) void fused_kernel(
    const float* __restrict__ x,    // [64][28][28]
    const float* __restrict__ w1,   // [128][32][3][3][2]
    const float* __restrict__ w2,   // [64][3][2]
    float* __restrict__ y)          // [128][28][28]
{
    __shared__ __align__(16) float sA[64 * 220];   // 56,320 B

    const int b     = blockIdx.x;     // 0..447
    const int opair = b / 7;
    const int band  = b % 7;
    const int tid   = threadIdx.x;

    // ---------------- Phase B thread mapping (needed for prefetch) --------
    const int l8      = tid & 7;          // lane bits 0-2: l-split
    const int strip   = tid >> 3;         // 0..31, active < 28
    const bool act    = (strip < 28);
    const int sclp    = act ? strip : 0;
    const int oo      = sclp / 14;
    const int rem     = sclp % 14;
    const int rp      = rem / 7;          // output row-pair within band
    const int st      = rem % 7;          // 4-col strip
    const int o       = opair * 2 + oo;

    // ---------------- Weight prefetch (before phase A) ----------------
    float2 wreg[4][9];
    {
        const float* wb = w1 + o * 576 + l8 * 18;   // w1[o][l][dy][s][k]
        #pragma unroll
        for (int li = 0; li < 4; ++li)
            #pragma unroll
            for (int t = 0; t < 9; ++t)
                wreg[li][t] = *(const float2*)(wb + li * 144 + t * 2);
    }

    // ---------------- Phase A: stage1+2 into LDS (l-paired) ----------------
    if (tid < 192) {
        const int l  = tid / 6;            // 0..31
        const int pr = tid % 6;            // padded row 0..5
        const int m  = band * 4 + pr - 1;  // input row
        const int j0 = 2 * l;
        float* dst0 = &sA[(2 * l)     * 220 + pr * 36];  // k=0 channel
        float* dst1 = &sA[(2 * l + 1) * 220 + pr * 36];  // k=1 channel
        if (m < 0 || m > 27) {
            #pragma unroll
            for (int t = 0; t < 7; ++t) {
                ((float4*)dst0)[t] = make_float4(0.f, 0.f, 0.f, 0.f);
                ((float4*)dst1)[t] = make_float4(0.f, 0.f, 0.f, 0.f);
            }
            ((float2*)dst0)[14] = make_float2(0.f, 0.f);
            ((float2*)dst1)[14] = make_float2(0.f, 0.f);
        } else {
            const float* xr0 = x + (j0 * 28 + m) * 28;
            const float* xr1 = xr0 + 28 * 28;
            // w2[j][i][k]: float2 at (j,i) = (k0, k1) pair
            const float2 a0 = *(const float2*)(w2 + j0 * 6 + 0);
            const float2 a1 = *(const float2*)(w2 + j0 * 6 + 2);
            const float2 a2 = *(const float2*)(w2 + j0 * 6 + 4);
            const float2 b0 = *(const float2*)(w2 + j0 * 6 + 6);
            const float2 b1 = *(const float2*)(w2 + j0 * 6 + 8);
            const float2 b2 = *(const float2*)(w2 + j0 * 6 + 10);

            float4 pv0 = make_float4(0.f, 0.f, 0.f, 0.f);
            float4 pv1 = make_float4(0.f, 0.f, 0.f, 0.f);
            #pragma unroll
            for (int t = 0; t < 7; ++t) {
                float4 v0 = ((const float4*)xr0)[t];
                float4 v1 = ((const float4*)xr1)[t];
                float4 o0, o1;
                o0.x = a0.x * pv0.z + a1.x * pv0.w + a2.x * v0.x
                     + b0.x * pv1.z + b1.x * pv1.w + b2.x * v1.x;
                o0.y = a0.x * pv0.w + a1.x * v0.x + a2.x * v0.y
                     + b0.x * pv1.w + b1.x * v1.x + b2.x * v1.y;
                o0.z = a0.x * v0.x + a1.x * v0.y + a2.x * v0.z
                     + b0.x * v1.x + b1.x * v1.y + b2.x * v1.z;
                o0.w = a0.x * v0.y + a1.x * v0.z + a2.x * v0.w
                     + b0.x * v1.y + b1.x * v1.z + b2.x * v1.w;
                o1.x = a0.y * pv0.z + a1.y * pv0.w + a2.y * v0.x
                     + b0.y * pv1.z + b1.y * pv1.w + b2.y * v1.x;
                o1.y = a0.y * pv0.w + a1.y * v0.x + a2.y * v0.y
                     + b0.y * pv1.w + b1.y * v1.x + b2.y * v1.y;
                o1.z = a0.y * v0.x + a1.y * v0.y + a2.y * v0.z
                     + b0.y * v1.x + b1.y * v1.y + b2.y * v1.z;
                o1.w = a0.y * v0.y + a1.y * v0.z + a2.y * v0.w
                     + b0.y * v1.y + b1.y * v1.z + b2.y * v1.w;
                if (t == 0) { o0.x = 0.f; o1.x = 0.f; }  // px 0 left zero-pad
                ((float4*)dst0)[t] = o0;
                ((float4*)dst1)[t] = o1;
                pv0 = v0; pv1 = v1;
            }
            // px 28 (taps xr[26], xr[27]) and px 29 (right pad)
            float t28_0 = a0.x * pv0.z + a1.x * pv0.w
                        + b0.x * pv1.z + b1.x * pv1.w;
            float t28_1 = a0.y * pv0.z + a1.y * pv0.w
                        + b0.y * pv1.z + b1.y * pv1.w;
            ((float2*)dst0)[14] = make_float2(t28_0, 0.f);
            ((float2*)dst1)[14] = make_float2(t28_1, 0.f);
        }
    }
    __syncthreads();

    // ---------------- Phase B: 3x3x64 conv, 2x4 tile ----------------
    float acc00 = 0.f, acc01 = 0.f, acc02 = 0.f, acc03 = 0.f;
    float acc10 = 0.f, acc11 = 0.f, acc12 = 0.f, acc13 = 0.f;

    #pragma unroll
    for (int li = 0; li < 4; ++li) {
        #pragma unroll
        for (int ch = 0; ch < 2; ++ch) {
            const int c = (l8 + li * 8) * 2 + ch;
            const float* sa = &sA[c * 220 + (rp * 2) * 36 + st * 4];
            #pragma unroll
            for (int q = 0; q < 4; ++q) {
                float4 t0 = *(const float4*)(sa + q * 36);
                float2 t1 = *(const float2*)(sa + q * 36 + 4);
                if (q < 3) {            // output row 0, tap dy=q
                    float2 W0 = wreg[li][q * 3 + 0];
                    float2 W1 = wreg[li][q * 3 + 1];
                    float2 W2 = wreg[li][q * 3 + 2];
                    float wa  = ch ? W0.y : W0.x;
                    float wbv = ch ? W1.y : W1.x;
                    float wc  = ch ? W2.y : W2.x;
                    acc00 += wa * t0.x + wbv * t0.y + wc * t0.z;
                    acc01 += wa * t0.y + wbv * t0.z + wc * t0.w;
                    acc02 += wa * t0.z + wbv * t0.w + wc * t1.x;
                    acc03 += wa * t0.w + wbv * t1.x + wc * t1.y;
                }
                if (q >= 1) {           // output row 1, tap dy=q-1
                    float2 W0 = wreg[li][(q - 1) * 3 + 0];
                    float2 W1 = wreg[li][(q - 1) * 3 + 1];
                    float2 W2 = wreg[li][(q - 1) * 3 + 2];
                    float wa  = ch ? W0.y : W0.x;
                    float wbv = ch ? W1.y : W1.x;
                    float wc  = ch ? W2.y : W2.x;
                    acc10 += wa * t0.x + wbv * t0.y + wc * t0.z;
                    acc11 += wa * t0.y + wbv * t0.z + wc * t0.w;
                    acc12 += wa * t0.z + wbv * t0.w + wc * t1.x;
                    acc13 += wa * t0.w + wbv * t1.x + wc * t1.y;
                }
            }
        }
    }

    // butterfly reduce over l8 (lane bits 0-2)
    #pragma unroll
    for (int m = 1; m <= 4; m <<= 1) {
        acc00 += __shfl_xor(acc00, m); acc01 += __shfl_xor(acc01, m);
        acc02 += __shfl_xor(acc02, m); acc03 += __shfl_xor(acc03, m);
        acc10 += __shfl_xor(acc10, m); acc11 += __shfl_xor(acc11, m);
        acc12 += __shfl_xor(acc12, m); acc13 += __shfl_xor(acc13, m);
    }

    if (act && l8 == 0) {
        const int R0 = band * 4 + rp * 2;
        float* yp = y + (o * 28 + R0) * 28 + st * 4;
        *(float4*)yp        = make_float4(acc00, acc01, acc02, acc03);
        *(float4*)(yp + 28) = make_float4(acc10, acc11, acc12, acc13);
    }
}

extern "C" void kernel_launch(void* const* d_in, const int* in_sizes, int n_in,
                              void* d_out, int out_size, void* d_ws, size_t ws_size,
                              hipStream_t stream) {
    const float* x  = (const float*)d_in[0];   // (1,64,28,28) fp32
    const float* w1 = (const float*)d_in[1];   // (128,32,3,3,2) fp32
    const float* w2 = (const float*)d_in[2];   // (64,3,2) fp32
    float* yout = (float*)d_out;               // (1,128,28,28) fp32

    fused_kernel<<<dim3(448), dim3(256), 0, stream>>>(x, w1, w2, yout);
}